// Round 9
// baseline (184.027 us; speedup 1.0000x reference)
//
#include <hip/hip_runtime.h>

#define NTAG 32
#define START 30
#define STOP 31
#define LOG2E 1.44269504088896340736f
#define LN2 0.69314718055994530942f

__device__ __forceinline__ float fexp2(float x) {
#if __has_builtin(__builtin_amdgcn_exp2f)
    return __builtin_amdgcn_exp2f(x);   // v_exp_f32: 2^x
#else
    return exp2f(x);
#endif
}
__device__ __forceinline__ float flog2(float x) {
#if __has_builtin(__builtin_amdgcn_logf)
    return __builtin_amdgcn_logf(x);    // v_log_f32: log2(x)
#else
    return log2f(x);
#endif
}

#define REPEAT32(M) \
    M(0) M(1) M(2) M(3) M(4) M(5) M(6) M(7) \
    M(8) M(9) M(10) M(11) M(12) M(13) M(14) M(15) \
    M(16) M(17) M(18) M(19) M(20) M(21) M(22) M(23) \
    M(24) M(25) M(26) M(27) M(28) M(29) M(30) M(31)

// 4 parallel accumulator chains fed by one float4 LDS read
#define FMA4(vr, i0, i1, i2, i3) \
    a0_ = fmaf(vr.x, ET2_##i0, a0_); a1_ = fmaf(vr.y, ET2_##i1, a1_); \
    a2_ = fmaf(vr.z, ET2_##i2, a2_); a3_ = fmaf(vr.w, ET2_##i3, a3_);

// One LINEAR-domain scan step with LDS broadcast (replaces 32x v_readlane).
// Chain: S -> ds_write -> 8x ds_read_b128 (same-addr broadcast, conflict-free)
//        -> 32 all-VGPR FMA (4 chains) -> merge -> *F.
// F = 2^(feat*log2e) comes from the prefetched feat (off-chain).
// RN: exact power-of-2 renorm via integer exponent subtract; k from lane0's
// exponent; cross-tag spread <= ~2^17 so no exponent wrap.
#define SCAN_STEP(FS, tcur, RN) { \
    const float fraw_ = FS; \
    { const int tn_ = (tcur) + 8; const int tc_ = (tn_ < L - 1) ? tn_ : (L - 1); \
      FS = frow[tc_ * NTAG + j]; } \
    const float F_ = fexp2(fraw_ * LOG2E); \
    sb[j] = S; \
    const float4 v0_ = sb4[0], v1_ = sb4[1], v2_ = sb4[2], v3_ = sb4[3]; \
    const float4 v4_ = sb4[4], v5_ = sb4[5], v6_ = sb4[6], v7_ = sb4[7]; \
    float a0_ = 0.f, a1_ = 0.f, a2_ = 0.f, a3_ = 0.f; \
    FMA4(v0_,  0,  1,  2,  3)  FMA4(v1_,  4,  5,  6,  7) \
    FMA4(v2_,  8,  9, 10, 11)  FMA4(v3_, 12, 13, 14, 15) \
    FMA4(v4_, 16, 17, 18, 19)  FMA4(v5_, 20, 21, 22, 23) \
    FMA4(v6_, 24, 25, 26, 27)  FMA4(v7_, 28, 29, 30, 31) \
    S = ((a0_ + a1_) + (a2_ + a3_)) * F_; \
    if (RN) { \
        const int b0_ = __builtin_amdgcn_readfirstlane(__float_as_int(S)); \
        const int k_ = ((b0_ >> 23) & 0xff) - 127; \
        S = __int_as_float(__float_as_int(S) - (k_ << 23)); \
        M2i += k_; \
    } }

// Block = 512 threads = 8 waves. Waves 0-3: serial alpha scan (linear domain),
// one batch each (lanes 0-31 = tags). Waves 4-7: gold-score gathers.
// Grid = B/4 = 256 blocks = 1 block/CU.
__global__ __launch_bounds__(512, 2) void crf_nll_kernel(
    const float* __restrict__ feats,   // B x L x 32
    const float* __restrict__ trans,   // 32 x 32
    const int*   __restrict__ tags,    // B x L
    const int*   __restrict__ wsl,     // B
    float* __restrict__ out, int B, int L)
{
    __shared__ float strans[NTAG * NTAG];
    __shared__ float sbuf[4][NTAG];    // per-scan-wave S broadcast buffer
    for (int i = threadIdx.x; i < NTAG * NTAG; i += 512) strans[i] = trans[i];
    __syncthreads();

    const int wave = threadIdx.x >> 6;
    const int lane = threadIdx.x & 63;

    if (wave < 4) {
        // ================= scan waves =================
        int b = blockIdx.x * 4 + wave;
        b = __builtin_amdgcn_readfirstlane(b);
        if (lane >= 32 || b >= B) return;
        const int j = lane;
        float* __restrict__ sb = &sbuf[wave][0];          // wave-uniform base
        const float4* __restrict__ sb4 = (const float4*)sb;

        // linear transition matrix column j: ET2_i = 2^(trans[i][j]*log2e)
#define DECL_ET2(i) float ET2_##i = fexp2(strans[(i) * NTAG + j] * LOG2E);
        REPEAT32(DECL_ET2)
#undef DECL_ET2
        const float tS2 = strans[j * NTAG + STOP] * LOG2E;

        const int n = wsl[b];
        const float* __restrict__ frow = feats + (size_t)b * L * NTAG;

        // init (t = 0): S_j = 2^((trans[START][j]+feat0_j)*log2e), M2i = 0
        // invariant: alpha_j(t) = ln2 * (M2i + log2 S_j)
        float S = fexp2((strans[START * NTAG + j] + frow[j]) * LOG2E);
        int M2i = 0;

        // prefetch ring: 8 named slots (f0 = oldest), raw feats
#define LDF(t_) frow[(((t_) < L - 1) ? (t_) : (L - 1)) * NTAG + j]
        float f0 = LDF(1), f1 = LDF(2), f2 = LDF(3), f3 = LDF(4),
              f4 = LDF(5), f5 = LDF(6), f6 = LDF(7), f7 = LDF(8);
#undef LDF

        int t = 1;
        for (; t + 8 <= n; t += 8) {
            // pin ET2 in VGPRs (zero-instruction insurance against remat/spill)
            asm volatile("" : "+v"(ET2_0),  "+v"(ET2_1),  "+v"(ET2_2),  "+v"(ET2_3),
                              "+v"(ET2_4),  "+v"(ET2_5),  "+v"(ET2_6),  "+v"(ET2_7));
            asm volatile("" : "+v"(ET2_8),  "+v"(ET2_9),  "+v"(ET2_10), "+v"(ET2_11),
                              "+v"(ET2_12), "+v"(ET2_13), "+v"(ET2_14), "+v"(ET2_15));
            asm volatile("" : "+v"(ET2_16), "+v"(ET2_17), "+v"(ET2_18), "+v"(ET2_19),
                              "+v"(ET2_20), "+v"(ET2_21), "+v"(ET2_22), "+v"(ET2_23));
            asm volatile("" : "+v"(ET2_24), "+v"(ET2_25), "+v"(ET2_26), "+v"(ET2_27),
                              "+v"(ET2_28), "+v"(ET2_29), "+v"(ET2_30), "+v"(ET2_31));
            SCAN_STEP(f0, t + 0, 0)
            SCAN_STEP(f1, t + 1, 0)
            SCAN_STEP(f2, t + 2, 0)
            SCAN_STEP(f3, t + 3, 1)   // renorm every 4 steps (exact pow2)
            SCAN_STEP(f4, t + 4, 0)
            SCAN_STEP(f5, t + 5, 0)
            SCAN_STEP(f6, t + 6, 0)
            SCAN_STEP(f7, t + 7, 1)
        }
        // epilogue: up to 7 remaining steps; renorm every step (trivial cost)
        if (t + 0 < n) { SCAN_STEP(f0, t + 0, 1) }
        if (t + 1 < n) { SCAN_STEP(f1, t + 1, 1) }
        if (t + 2 < n) { SCAN_STEP(f2, t + 2, 1) }
        if (t + 3 < n) { SCAN_STEP(f3, t + 3, 1) }
        if (t + 4 < n) { SCAN_STEP(f4, t + 4, 1) }
        if (t + 5 < n) { SCAN_STEP(f5, t + 5, 1) }
        if (t + 6 < n) { SCAN_STEP(f6, t + 6, 1) }

        // forward score: ln2 * (M2i + log2 sum_j S_j * 2^(trans[j,STOP]*log2e))
        float ex = S * fexp2(tS2);
#pragma unroll
        for (int k = 1; k < 32; k <<= 1) ex += __shfl_xor(ex, k, 32);
        if (j == 0) atomicAdd(out, LN2 * ((float)M2i + flog2(ex)));
    } else {
        // ================= gold waves (pure gathers, fill scan stalls) =======
        int b = blockIdx.x * 4 + (wave - 4);
        b = __builtin_amdgcn_readfirstlane(b);
        if (b >= B) return;
        const int n = wsl[b];
        const float* __restrict__ frow = feats + (size_t)b * L * NTAG;
        const int*   __restrict__ trow = tags  + (size_t)b * L;

        float acc = 0.f;
        for (int t = lane; t < L; t += 64) {
            const int tg = trow[t];
            if (t == 0) {
                acc += strans[START * NTAG + tg] + frow[tg];
            } else if (t < n) {
                const int tgp = trow[t - 1];
                acc += strans[tgp * NTAG + tg] + frow[t * NTAG + tg];
            }
            if (t == n - 1) {
                acc += strans[tg * NTAG + STOP];
            }
        }
#pragma unroll
        for (int k = 1; k < 64; k <<= 1) acc += __shfl_xor(acc, k, 64);
        if (lane == 0) atomicAdd(out, -acc);
    }
}

extern "C" void kernel_launch(void* const* d_in, const int* in_sizes, int n_in,
                              void* d_out, int out_size, void* d_ws, size_t ws_size,
                              hipStream_t stream) {
    const float* feats = (const float*)d_in[0];
    const float* trans = (const float*)d_in[1];
    const int*   tags  = (const int*)d_in[2];
    const int*   wsl   = (const int*)d_in[3];
    float* out = (float*)d_out;

    const int B = in_sizes[3];              // word_seq_lens: (B,)
    const int L = in_sizes[2] / B;          // tags: (B, L)

    (void)hipMemsetAsync(out, 0, sizeof(float), stream);
    const int grid = (B + 3) / 4;
    crf_nll_kernel<<<grid, 512, 0, stream>>>(feats, trans, tags, wsl, out, B, L);
}

// Round 10
// 172.713 us; speedup vs baseline: 1.0655x; 1.0655x over previous
//
#include <hip/hip_runtime.h>

#define NTAG 32
#define START 30
#define STOP 31
#define LOG2E 1.44269504088896340736f
#define LN2 0.69314718055994530942f

__device__ __forceinline__ float fexp2(float x) {
#if __has_builtin(__builtin_amdgcn_exp2f)
    return __builtin_amdgcn_exp2f(x);   // v_exp_f32: 2^x
#else
    return exp2f(x);
#endif
}
__device__ __forceinline__ float flog2(float x) {
#if __has_builtin(__builtin_amdgcn_logf)
    return __builtin_amdgcn_logf(x);    // v_log_f32: log2(x)
#else
    return log2f(x);
#endif
}

#define REPEAT32(M) \
    M(0) M(1) M(2) M(3) M(4) M(5) M(6) M(7) \
    M(8) M(9) M(10) M(11) M(12) M(13) M(14) M(15) \
    M(16) M(17) M(18) M(19) M(20) M(21) M(22) M(23) \
    M(24) M(25) M(26) M(27) M(28) M(29) M(30) M(31)

// batched readlanes of linear state S (all before any FMA)
#define RL_DECL(i) const int su_##i = __builtin_amdgcn_readlane(sint_, (i));
// 4-way accumulator FMA block: d_j = sum_i S_i * ET[i][j]
#define FMA_T(i) { const float sf_ = __int_as_float(su_##i); \
    if      (((i) & 3) == 0) a0_ = fmaf(sf_, ET2_##i, a0_); \
    else if (((i) & 3) == 1) a1_ = fmaf(sf_, ET2_##i, a1_); \
    else if (((i) & 3) == 2) a2_ = fmaf(sf_, ET2_##i, a2_); \
    else                     a3_ = fmaf(sf_, ET2_##i, a3_); }

// Core of one LINEAR-domain scan step (no prefetch inside).
// Chain: readlane(S) -> fma tree -> merge -> *F.  F = 2^(feat*log2e).
// RN: exact power-of-2 renorm via integer exponent subtract (lane0's exp).
#define STEP_CORE(fraw_, RN) { \
    const float F_ = fexp2((fraw_) * LOG2E); \
    const int sint_ = __float_as_int(S); \
    REPEAT32(RL_DECL) \
    float a0_ = 0.f, a1_ = 0.f, a2_ = 0.f, a3_ = 0.f; \
    REPEAT32(FMA_T) \
    S = ((a0_ + a1_) + (a2_ + a3_)) * F_; \
    if (RN) { \
        const int b0_ = __builtin_amdgcn_readfirstlane(__float_as_int(S)); \
        const int k_ = ((b0_ >> 23) & 0xff) - 127; \
        S = __int_as_float(__float_as_int(S) - (k_ << 23)); \
        M2i += k_; \
    } }

// Consume slot FS (feat for its time step) and IMMEDIATELY reload it with
// time index tload (16 steps ahead). No register rotation movs -> the
// consume waits on a load issued 16 steps (~3000 cy) earlier, never the
// one-step-old load that the old ring rotation serialized on.
#define STEP_RELOAD(FS, tload, RN) { \
    const float fraw_ = FS; \
    { const int tc_ = ((tload) < L - 1) ? (tload) : (L - 1); \
      FS = frow[tc_ * NTAG + j]; } \
    STEP_CORE(fraw_, RN) }

// Consume slot FS without reloading (epilogue).
#define STEP_NORELOAD(FS, RN) { const float fraw_ = FS; STEP_CORE(fraw_, RN) }

// Block = 512 threads = 8 waves. Waves 0-3: serial alpha scan (linear domain),
// one batch each (lanes 0-31 = tags). Waves 4-7: gold-score gathers.
// Grid = B/4 = 256 blocks = 1 block/CU.
__global__ __launch_bounds__(512, 2) void crf_nll_kernel(
    const float* __restrict__ feats,   // B x L x 32
    const float* __restrict__ trans,   // 32 x 32
    const int*   __restrict__ tags,    // B x L
    const int*   __restrict__ wsl,     // B
    float* __restrict__ out, int B, int L)
{
    __shared__ float strans[NTAG * NTAG];
    for (int i = threadIdx.x; i < NTAG * NTAG; i += 512) strans[i] = trans[i];
    __syncthreads();

    const int wave = threadIdx.x >> 6;
    const int lane = threadIdx.x & 63;

    if (wave < 4) {
        // ================= scan waves =================
        int b = blockIdx.x * 4 + wave;
        b = __builtin_amdgcn_readfirstlane(b);
        if (lane >= 32 || b >= B) return;
        const int j = lane;

        // linear transition matrix column j: ET2_i = 2^(trans[i][j]*log2e)
#define DECL_ET2(i) float ET2_##i = fexp2(strans[(i) * NTAG + j] * LOG2E);
        REPEAT32(DECL_ET2)
#undef DECL_ET2
        const float tS2 = strans[j * NTAG + STOP] * LOG2E;

        const int n = wsl[b];
        const float* __restrict__ frow = feats + (size_t)b * L * NTAG;

        // init (t = 0): S_j = 2^((trans[START][j]+feat0_j)*log2e), M2i = 0
        // invariant: alpha_j(t) = ln2 * (M2i + log2 S_j)
        float S = fexp2((strans[START * NTAG + j] + frow[j]) * LOG2E);
        int M2i = 0;

        // two prefetch groups of 8 named slots; invariant at loop head:
        //   fA_i = feat(t + i),  fB_i = feat(t + 8 + i)
#define LDF(t_) frow[(((t_) < L - 1) ? (t_) : (L - 1)) * NTAG + j]
        float fA0 = LDF(1),  fA1 = LDF(2),  fA2 = LDF(3),  fA3 = LDF(4),
              fA4 = LDF(5),  fA5 = LDF(6),  fA6 = LDF(7),  fA7 = LDF(8);
        float fB0 = LDF(9),  fB1 = LDF(10), fB2 = LDF(11), fB3 = LDF(12),
              fB4 = LDF(13), fB5 = LDF(14), fB6 = LDF(15), fB7 = LDF(16);
#undef LDF

        int t = 1;
        for (; t + 16 <= n; t += 16) {
            // pin ET2 in VGPRs (zero-instruction insurance against remat/spill)
            asm volatile("" : "+v"(ET2_0),  "+v"(ET2_1),  "+v"(ET2_2),  "+v"(ET2_3),
                              "+v"(ET2_4),  "+v"(ET2_5),  "+v"(ET2_6),  "+v"(ET2_7));
            asm volatile("" : "+v"(ET2_8),  "+v"(ET2_9),  "+v"(ET2_10), "+v"(ET2_11),
                              "+v"(ET2_12), "+v"(ET2_13), "+v"(ET2_14), "+v"(ET2_15));
            asm volatile("" : "+v"(ET2_16), "+v"(ET2_17), "+v"(ET2_18), "+v"(ET2_19),
                              "+v"(ET2_20), "+v"(ET2_21), "+v"(ET2_22), "+v"(ET2_23));
            asm volatile("" : "+v"(ET2_24), "+v"(ET2_25), "+v"(ET2_26), "+v"(ET2_27),
                              "+v"(ET2_28), "+v"(ET2_29), "+v"(ET2_30), "+v"(ET2_31));
            // steps t .. t+7 consume group A, reload A <- t+16 .. t+23
            STEP_RELOAD(fA0, t + 16, 0)
            STEP_RELOAD(fA1, t + 17, 0)
            STEP_RELOAD(fA2, t + 18, 0)
            STEP_RELOAD(fA3, t + 19, 1)   // exact pow2 renorm every 4 steps
            STEP_RELOAD(fA4, t + 20, 0)
            STEP_RELOAD(fA5, t + 21, 0)
            STEP_RELOAD(fA6, t + 22, 0)
            STEP_RELOAD(fA7, t + 23, 1)
            // steps t+8 .. t+15 consume group B, reload B <- t+24 .. t+31
            STEP_RELOAD(fB0, t + 24, 0)
            STEP_RELOAD(fB1, t + 25, 0)
            STEP_RELOAD(fB2, t + 26, 0)
            STEP_RELOAD(fB3, t + 27, 1)
            STEP_RELOAD(fB4, t + 28, 0)
            STEP_RELOAD(fB5, t + 29, 0)
            STEP_RELOAD(fB6, t + 30, 0)
            STEP_RELOAD(fB7, t + 31, 1)
        }
        // epilogue: remaining n-t in [0,16); A holds t..t+7, B holds t+8..t+15
        if (t + 0  < n) { STEP_NORELOAD(fA0, 1) }
        if (t + 1  < n) { STEP_NORELOAD(fA1, 1) }
        if (t + 2  < n) { STEP_NORELOAD(fA2, 1) }
        if (t + 3  < n) { STEP_NORELOAD(fA3, 1) }
        if (t + 4  < n) { STEP_NORELOAD(fA4, 1) }
        if (t + 5  < n) { STEP_NORELOAD(fA5, 1) }
        if (t + 6  < n) { STEP_NORELOAD(fA6, 1) }
        if (t + 7  < n) { STEP_NORELOAD(fA7, 1) }
        if (t + 8  < n) { STEP_NORELOAD(fB0, 1) }
        if (t + 9  < n) { STEP_NORELOAD(fB1, 1) }
        if (t + 10 < n) { STEP_NORELOAD(fB2, 1) }
        if (t + 11 < n) { STEP_NORELOAD(fB3, 1) }
        if (t + 12 < n) { STEP_NORELOAD(fB4, 1) }
        if (t + 13 < n) { STEP_NORELOAD(fB5, 1) }
        if (t + 14 < n) { STEP_NORELOAD(fB6, 1) }

        // forward score: ln2 * (M2i + log2 sum_j S_j * 2^(trans[j,STOP]*log2e))
        float ex = S * fexp2(tS2);
#pragma unroll
        for (int k = 1; k < 32; k <<= 1) ex += __shfl_xor(ex, k, 32);
        if (j == 0) atomicAdd(out, LN2 * ((float)M2i + flog2(ex)));
    } else {
        // ================= gold waves (pure gathers, fill scan stalls) =======
        int b = blockIdx.x * 4 + (wave - 4);
        b = __builtin_amdgcn_readfirstlane(b);
        if (b >= B) return;
        const int n = wsl[b];
        const float* __restrict__ frow = feats + (size_t)b * L * NTAG;
        const int*   __restrict__ trow = tags  + (size_t)b * L;

        float acc = 0.f;
        for (int t = lane; t < L; t += 64) {
            const int tg = trow[t];
            if (t == 0) {
                acc += strans[START * NTAG + tg] + frow[tg];
            } else if (t < n) {
                const int tgp = trow[t - 1];
                acc += strans[tgp * NTAG + tg] + frow[t * NTAG + tg];
            }
            if (t == n - 1) {
                acc += strans[tg * NTAG + STOP];
            }
        }
#pragma unroll
        for (int k = 1; k < 64; k <<= 1) acc += __shfl_xor(acc, k, 64);
        if (lane == 0) atomicAdd(out, -acc);
    }
}

extern "C" void kernel_launch(void* const* d_in, const int* in_sizes, int n_in,
                              void* d_out, int out_size, void* d_ws, size_t ws_size,
                              hipStream_t stream) {
    const float* feats = (const float*)d_in[0];
    const float* trans = (const float*)d_in[1];
    const int*   tags  = (const int*)d_in[2];
    const int*   wsl   = (const int*)d_in[3];
    float* out = (float*)d_out;

    const int B = in_sizes[3];              // word_seq_lens: (B,)
    const int L = in_sizes[2] / B;          // tags: (B, L)

    (void)hipMemsetAsync(out, 0, sizeof(float), stream);
    const int grid = (B + 3) / 4;
    crf_nll_kernel<<<grid, 512, 0, stream>>>(feats, trans, tags, wsl, out, B, L);
}